// Round 8
// baseline (533.806 us; speedup 1.0000x reference)
//
#include <hip/hip_runtime.h>

#define BB   1024
#define TT   512
#define NIN  28
#define NOUT 28
#define NS   4
#define MM   7
#define WW   457          // TT - NIN - NOUT + 1
#define SLEN 519          // MM + 1 + TT - 1
#define EMB  9            // 1 + 1 + MM

#define OUT1_SZ (WW * BB * 144)
#define OUT2_SZ (WW * BB * 28)
#define OUT3_SZ (BB * TT)
#define OUT4_SZ (BB * SLEN)

#define CH   32
#define NCH  (TT / CH)    // 16

#define REPS 4            // DIAGNOSTIC: repeat store phase to surface counters

typedef float f4 __attribute__((ext_vector_type(4)));

__device__ __forceinline__ f4 ld4u(const float* p) {
    f4 v;
    __builtin_memcpy(&v, p, sizeof(f4));
    return v;
}

// ---------------------------------------------------------------------------
// Kernel 1: ES scan (unchanged, ~10 us). Plain stores: levels/seas are
// re-read by lds_stream, keep them cacheable.
// ---------------------------------------------------------------------------
__global__ __launch_bounds__(64) void es_scan(const float* __restrict__ Y,
        const int* __restrict__ idxs, const float* __restrict__ EW,
        float* __restrict__ levels, float* __restrict__ seas) {
    __shared__ float yl[64][CH + 1];
    __shared__ float se[64][CH + 1];
    const int tid = threadIdx.x;
    const int b0  = blockIdx.x << 6;
    const int b   = b0 + tid;

    const float* e = EW + idxs[b] * EMB;
    const float lev_sms  = 1.0f / (1.0f + __expf(-e[0]));
    const float seas_sms = 1.0f / (1.0f + __expf(-e[1]));
    const float a_l = 1.0f - lev_sms;
    const float a_s = 1.0f - seas_sms;

    float buf[MM];
    const float is0 = __expf(e[2]);
    {
        float* srow = seas + b * SLEN;
        srow[0] = is0;
#pragma unroll
        for (int k = 1; k < MM; ++k) {
            float v = __expf(e[2 + k]);
            srow[k] = v;
            buf[k - 1] = v;
        }
        buf[MM - 1] = is0;
    }

    f4 pf[8];
#pragma unroll
    for (int k = 0; k < 8; ++k) {
        int flat = (k << 6) + tid;
        int r = flat >> 3, q = flat & 7;
        pf[k] = *reinterpret_cast<const f4*>(Y + (b0 + r) * TT + (q << 2));
    }

    float lev = 0.0f;

#define ES_STEP(TTI)                                                        \
    {                                                                       \
        float y  = yreg[TTI];                                               \
        float st = buf[0];                                                  \
        lev = lev_sms * __fdividef(y, st) + a_l * lev;                      \
        float ns = seas_sms * __fdividef(y, lev) + a_s * st;                \
        buf[0] = buf[1]; buf[1] = buf[2]; buf[2] = buf[3];                  \
        buf[3] = buf[4]; buf[4] = buf[5]; buf[5] = buf[6];                  \
        buf[6] = ns;                                                        \
        yl[tid][TTI] = lev;                                                 \
        se[tid][TTI] = ns;                                                  \
    }

    for (int c = 0; c < NCH; ++c) {
        __syncthreads();
#pragma unroll
        for (int k = 0; k < 8; ++k) {
            int flat = (k << 6) + tid;
            int r = flat >> 3, q = flat & 7;
            float* dst = &yl[r][q << 2];
            dst[0] = pf[k].x; dst[1] = pf[k].y; dst[2] = pf[k].z; dst[3] = pf[k].w;
        }
        __syncthreads();
        if (c < NCH - 1) {
#pragma unroll
            for (int k = 0; k < 8; ++k) {
                int flat = (k << 6) + tid;
                int r = flat >> 3, q = flat & 7;
                pf[k] = *reinterpret_cast<const f4*>(
                    Y + (b0 + r) * TT + (c + 1) * CH + (q << 2));
            }
        }

        float yreg[CH];
#pragma unroll
        for (int tt = 0; tt < CH; ++tt) yreg[tt] = yl[tid][tt];

        if (c == 0) {
            lev = __fdividef(yreg[0], is0);
            yl[tid][0] = lev;
            se[tid][0] = is0;
#pragma unroll
            for (int tt = 1; tt < CH; ++tt) ES_STEP(tt)
        } else {
#pragma unroll
            for (int tt = 0; tt < CH; ++tt) ES_STEP(tt)
        }
        __syncthreads();

#pragma unroll
        for (int k = 0; k < CH; ++k) {
            int flat = (k << 6) + tid;
            int r    = flat >> 5;
            int col  = flat & 31;
            levels[(b0 + r) * TT   + c * CH + col]      = yl[r][col];
            seas  [(b0 + r) * SLEN + MM + c * CH + col] = se[r][col];
        }
    }
#undef ES_STEP
}

// ---------------------------------------------------------------------------
// Kernel 2: LDS-staged streaming (R7 structure) + NT stores + REPS passes.
// Reads each global input byte exactly once; all reuse from LDS. Store
// phase repeated REPS times with identical data (diagnostic visibility).
// ---------------------------------------------------------------------------
#define NJ1 (WW * 72)
#define NJ2 (WW * 14)

__global__ __launch_bounds__(256) void lds_stream(const float* __restrict__ S,
        const float* __restrict__ Y, const float* __restrict__ X,
        const float* __restrict__ mask, const float* __restrict__ levels,
        const float* __restrict__ seas, f4* __restrict__ out1,
        f4* __restrict__ out2, f4* __restrict__ out5) {
    __shared__ float X0[2][TT];
    __shared__ float X1[2][TT];
    __shared__ float Yl[2][TT];
    __shared__ float Ml[2][TT];
    __shared__ float LV[2][TT];
    __shared__ float SEg[2][TT];
    __shared__ float Sl[2][NS];

    const int tid = threadIdx.x;
    const int b0  = blockIdx.x << 1;

    {
        int r = tid >> 7;
        int q = (tid & 127) << 2;
        int b = b0 + r;
        ((f4*)X0)[tid]  = *reinterpret_cast<const f4*>(X + (size_t)(b * 2    ) * TT + q);
        ((f4*)X1)[tid]  = *reinterpret_cast<const f4*>(X + (size_t)(b * 2 + 1) * TT + q);
        ((f4*)Yl)[tid]  = *reinterpret_cast<const f4*>(Y      + (size_t)b * TT + q);
        ((f4*)Ml)[tid]  = *reinterpret_cast<const f4*>(mask   + (size_t)b * TT + q);
        ((f4*)LV)[tid]  = *reinterpret_cast<const f4*>(levels + (size_t)b * TT + q);
        ((f4*)SEg)[tid] = ld4u(seas + (size_t)b * SLEN + q);
        if (tid < 8) Sl[tid >> 2][tid & 3] = S[(b0 + (tid >> 2)) * NS + (tid & 3)];
    }
    __syncthreads();

    for (int rep = 0; rep < REPS; ++rep) {
        for (int j = tid; j < NJ1; j += 256) {
            int w   = j / 72;
            int c   = j - w * 72;
            int bl  = (c >= 36) ? 1 : 0;
            int col = c - 36 * bl;
            f4 v;
            if (col < 7) {
                int idx  = w + (col << 2);
                float le = LV[bl][w + NIN - 1];
                v.x = __logf(__fdividef(Yl[bl][idx    ], le * SEg[bl][idx    ]));
                v.y = __logf(__fdividef(Yl[bl][idx + 1], le * SEg[bl][idx + 1]));
                v.z = __logf(__fdividef(Yl[bl][idx + 2], le * SEg[bl][idx + 2]));
                v.w = __logf(__fdividef(Yl[bl][idx + 3], le * SEg[bl][idx + 3]));
            } else if (col < 21) {
                int ix = w + ((col - 7) << 2);
                v.x = X0[bl][ix]; v.y = X0[bl][ix + 1];
                v.z = X0[bl][ix + 2]; v.w = X0[bl][ix + 3];
            } else if (col < 35) {
                int ix = w + ((col - 21) << 2);
                v.x = X1[bl][ix]; v.y = X1[bl][ix + 1];
                v.z = X1[bl][ix + 2]; v.w = X1[bl][ix + 3];
            } else {
                v.x = Sl[bl][0]; v.y = Sl[bl][1]; v.z = Sl[bl][2]; v.w = Sl[bl][3];
            }
            __builtin_nontemporal_store(v, &out1[((w << 10) + b0 + bl) * 36 + col]);
        }

        for (int j = tid; j < NJ2; j += 256) {
            int w  = j / 14;
            int c  = j - w * 14;
            int bl = (c >= 7) ? 1 : 0;
            int jj = c - 7 * bl;
            int idx = w + NIN + (jj << 2);
            f4 vy, vm;
            vy.x = Yl[bl][idx]; vy.y = Yl[bl][idx + 1];
            vy.z = Yl[bl][idx + 2]; vy.w = Yl[bl][idx + 3];
            vm.x = Ml[bl][idx]; vm.y = Ml[bl][idx + 1];
            vm.z = Ml[bl][idx + 2]; vm.w = Ml[bl][idx + 3];
            int o = ((w << 10) + b0 + bl) * 7 + jj;
            __builtin_nontemporal_store(vy, &out2[o]);
            __builtin_nontemporal_store(vm, &out5[o]);
        }
    }
}

extern "C" void kernel_launch(void* const* d_in, const int* in_sizes, int n_in,
                              void* d_out, int out_size, void* d_ws, size_t ws_size,
                              hipStream_t stream) {
    const float* S    = (const float*)d_in[0];
    const float* Y    = (const float*)d_in[1];
    const float* X    = (const float*)d_in[2];
    const int*   idxs = (const int*)d_in[3];
    const float* mask = (const float*)d_in[4];
    const float* EW   = (const float*)d_in[5];

    float* out  = (float*)d_out;
    float* out1 = out;
    float* out2 = out1 + OUT1_SZ;
    float* out3 = out2 + OUT2_SZ;        // levels
    float* out4 = out3 + OUT3_SZ;        // seasonalities
    float* out5 = out4 + OUT4_SZ;        // mask_w

    es_scan<<<16, 64, 0, stream>>>(Y, idxs, EW, out3, out4);
    lds_stream<<<BB / 2, 256, 0, stream>>>(S, Y, X, mask, out3, out4,
                                           (f4*)out1, (f4*)out2, (f4*)out5);
}

// Round 9
// 138.061 us; speedup vs baseline: 3.8665x; 3.8665x over previous
//
#include <hip/hip_runtime.h>

#define BB   1024
#define TT   512
#define NIN  28
#define NOUT 28
#define NS   4
#define MM   7
#define WW   457          // TT - NIN - NOUT + 1
#define SLEN 519          // MM + 1 + TT - 1
#define EMB  9            // 1 + 1 + MM

#define OUT1_SZ (WW * BB * 144)
#define OUT2_SZ (WW * BB * 28)
#define OUT3_SZ (BB * TT)
#define OUT4_SZ (BB * SLEN)

#define CH   32
#define NCH  (TT / CH)    // 16

typedef float f4 __attribute__((ext_vector_type(4)));

__device__ __forceinline__ f4 ld4u(const float* p) {   // 4B-aligned 16B load
    f4 v;
    __builtin_memcpy(&v, p, sizeof(f4));
    return v;
}

// ---------------------------------------------------------------------------
// Kernel 1: ES scan (unchanged, ~10 us). Plain stores keep levels/seas L2-hot
// for k_out1's staging reads.
// ---------------------------------------------------------------------------
__global__ __launch_bounds__(64) void es_scan(const float* __restrict__ Y,
        const int* __restrict__ idxs, const float* __restrict__ EW,
        float* __restrict__ levels, float* __restrict__ seas) {
    __shared__ float yl[64][CH + 1];
    __shared__ float se[64][CH + 1];
    const int tid = threadIdx.x;
    const int b0  = blockIdx.x << 6;
    const int b   = b0 + tid;

    const float* e = EW + idxs[b] * EMB;
    const float lev_sms  = 1.0f / (1.0f + __expf(-e[0]));
    const float seas_sms = 1.0f / (1.0f + __expf(-e[1]));
    const float a_l = 1.0f - lev_sms;
    const float a_s = 1.0f - seas_sms;

    float buf[MM];
    const float is0 = __expf(e[2]);
    {
        float* srow = seas + b * SLEN;
        srow[0] = is0;
#pragma unroll
        for (int k = 1; k < MM; ++k) {
            float v = __expf(e[2 + k]);
            srow[k] = v;
            buf[k - 1] = v;
        }
        buf[MM - 1] = is0;
    }

    f4 pf[8];
#pragma unroll
    for (int k = 0; k < 8; ++k) {
        int flat = (k << 6) + tid;
        int r = flat >> 3, q = flat & 7;
        pf[k] = *reinterpret_cast<const f4*>(Y + (b0 + r) * TT + (q << 2));
    }

    float lev = 0.0f;

#define ES_STEP(TTI)                                                        \
    {                                                                       \
        float y  = yreg[TTI];                                               \
        float st = buf[0];                                                  \
        lev = lev_sms * __fdividef(y, st) + a_l * lev;                      \
        float ns = seas_sms * __fdividef(y, lev) + a_s * st;                \
        buf[0] = buf[1]; buf[1] = buf[2]; buf[2] = buf[3];                  \
        buf[3] = buf[4]; buf[4] = buf[5]; buf[5] = buf[6];                  \
        buf[6] = ns;                                                        \
        yl[tid][TTI] = lev;                                                 \
        se[tid][TTI] = ns;                                                  \
    }

    for (int c = 0; c < NCH; ++c) {
        __syncthreads();
#pragma unroll
        for (int k = 0; k < 8; ++k) {
            int flat = (k << 6) + tid;
            int r = flat >> 3, q = flat & 7;
            float* dst = &yl[r][q << 2];
            dst[0] = pf[k].x; dst[1] = pf[k].y; dst[2] = pf[k].z; dst[3] = pf[k].w;
        }
        __syncthreads();
        if (c < NCH - 1) {
#pragma unroll
            for (int k = 0; k < 8; ++k) {
                int flat = (k << 6) + tid;
                int r = flat >> 3, q = flat & 7;
                pf[k] = *reinterpret_cast<const f4*>(
                    Y + (b0 + r) * TT + (c + 1) * CH + (q << 2));
            }
        }

        float yreg[CH];
#pragma unroll
        for (int tt = 0; tt < CH; ++tt) yreg[tt] = yl[tid][tt];

        if (c == 0) {
            lev = __fdividef(yreg[0], is0);
            yl[tid][0] = lev;
            se[tid][0] = is0;
#pragma unroll
            for (int tt = 1; tt < CH; ++tt) ES_STEP(tt)
        } else {
#pragma unroll
            for (int tt = 0; tt < CH; ++tt) ES_STEP(tt)
        }
        __syncthreads();

#pragma unroll
        for (int k = 0; k < CH; ++k) {
            int flat = (k << 6) + tid;
            int r    = flat >> 5;
            int col  = flat & 31;
            levels[(b0 + r) * TT   + c * CH + col]      = yl[r][col];
            seas  [(b0 + r) * SLEN + MM + c * CH + col] = se[r][col];
        }
    }
#undef ES_STEP
}

// ---------------------------------------------------------------------------
// Kernel 2: out1. Block = 2 batch rows. Shift-replicated LDS (4 copies at
// float offsets 0..3) => every window read is ONE aligned ds_read_b128,
// conflict-free (sub-arrays padded +1 f4 to stagger banks).
// log(y/(le*s)) = LYS[t] - LL[w+27], both precomputed at stage time.
// Flat col order per (w,b-pair): 72 f4 = 1152B = 9 aligned full lines,
// no cross-block line sharing => plain stores, no allocate fetch.
// ---------------------------------------------------------------------------
#define PD 129            // padded inner slot count (16B-aligned, bank-staggered)

__global__ __launch_bounds__(256) void k_out1(const float* __restrict__ S,
        const float* __restrict__ Y, const float* __restrict__ X,
        const float* __restrict__ levels, const float* __restrict__ seas,
        f4* __restrict__ out1) {
    __shared__ f4    Xr[4 * 2 * 2 * PD];   // [s][bl][ch][slot]
    __shared__ f4    LYSr[4 * 2 * PD];     // [s][bl][slot]
    __shared__ float LL[2][512];
    __shared__ float LYSp[2][520];

    const int tid = threadIdx.x;
    const int b0  = blockIdx.x << 1;

    // phase 0: per-element logs (coalesced global reads, all L2-hot)
    for (int u = tid; u < 1024; u += 256) {
        int bl = u >> 9, t = u & 511;
        int b  = b0 + bl;
        LL[bl][t]   = __logf(levels[b * TT + t]);
        LYSp[bl][t] = __logf(Y[b * TT + t]) - __logf(seas[b * SLEN + t]);
    }
    __syncthreads();

    // phase 1: build shifted replicas
    for (int u = tid; u < 1024; u += 256) {        // LYSr (s, bl, k)
        int s = u >> 8, r = u & 255, bl = r >> 7, k = r & 127;
        int base = 4 * k + s;                      // <= 511; +3 <= 514 < 520
        f4 v;
        v.x = LYSp[bl][base];     v.y = LYSp[bl][base + 1];
        v.z = LYSp[bl][base + 2]; v.w = LYSp[bl][base + 3];
        LYSr[(s * 2 + bl) * PD + k] = v;
    }
    for (int u = tid; u < 2048; u += 256) {        // Xr (s, bl, ch, k)
        int s = u >> 9, r = u & 511, bl = r >> 8, ch = (r >> 7) & 1, k = r & 127;
        int start = 4 * k + s; if (start > 508) start = 508;
        Xr[((s * 2 + bl) * 2 + ch) * PD + k] =
            ld4u(X + (size_t)((b0 + bl) * 2 + ch) * TT + start);
    }
    f4 Sv0 = *reinterpret_cast<const f4*>(S + b0 * NS);
    f4 Sv1 = *reinterpret_cast<const f4*>(S + (b0 + 1) * NS);
    __syncthreads();

    // main: flat (w, bl, col) — dense full-line plain stores
    for (int j = tid; j < WW * 72; j += 256) {
        int g   = j / 72;                           // w
        int r   = j - g * 72;
        int bl  = (r >= 36) ? 1 : 0;
        int col = r - 36 * bl;
        int s   = g & 3;
        int whi = g >> 2;
        f4 v;
        if (col < 7) {                              // log insample
            f4 t = LYSr[(s * 2 + bl) * PD + whi + col];
            float ll = LL[bl][g + 27];
            v.x = t.x - ll; v.y = t.y - ll; v.z = t.z - ll; v.w = t.w - ll;
        } else if (col < 35) {                      // X windows
            int ch = (col >= 21) ? 1 : 0;
            int jj = col - 7 - 14 * ch;             // 0..13
            v = Xr[((s * 2 + bl) * 2 + ch) * PD + whi + jj];
        } else {                                    // statics
            v = bl ? Sv1 : Sv0;
        }
        out1[((g << 10) + b0 + bl) * 36 + col] = v;
    }
}

// ---------------------------------------------------------------------------
// Kernel 3: out2 + out5. No LDS (Y/mask are L2-hot); flat dense i-mapping;
// plain stores.
// ---------------------------------------------------------------------------
#define NF2 (WW * BB * 7)

__global__ __launch_bounds__(256) void k_out25(const float* __restrict__ Y,
        const float* __restrict__ mask, f4* __restrict__ out2,
        f4* __restrict__ out5) {
    int i = blockIdx.x * blockDim.x + threadIdx.x;
    const int stride = gridDim.x * blockDim.x;
    for (; i < NF2; i += stride) {
        int wb = i / 7;
        int j  = i - wb * 7;
        int b  = wb & (BB - 1);
        int w  = wb >> 10;
        int base = w + NIN + (j << 2);
        out2[i] = ld4u(Y    + b * TT + base);
        out5[i] = ld4u(mask + b * TT + base);
    }
}

extern "C" void kernel_launch(void* const* d_in, const int* in_sizes, int n_in,
                              void* d_out, int out_size, void* d_ws, size_t ws_size,
                              hipStream_t stream) {
    const float* S    = (const float*)d_in[0];
    const float* Y    = (const float*)d_in[1];
    const float* X    = (const float*)d_in[2];
    const int*   idxs = (const int*)d_in[3];
    const float* mask = (const float*)d_in[4];
    const float* EW   = (const float*)d_in[5];

    float* out  = (float*)d_out;
    float* out1 = out;
    float* out2 = out1 + OUT1_SZ;
    float* out3 = out2 + OUT2_SZ;        // levels
    float* out4 = out3 + OUT3_SZ;        // seasonalities
    float* out5 = out4 + OUT4_SZ;        // mask_w

    es_scan<<<16, 64, 0, stream>>>(Y, idxs, EW, out3, out4);
    k_out1<<<BB / 2, 256, 0, stream>>>(S, Y, X, out3, out4, (f4*)out1);
    k_out25<<<2048, 256, 0, stream>>>(Y, mask, (f4*)out2, (f4*)out5);
}

// Round 10
// 129.966 us; speedup vs baseline: 4.1073x; 1.0623x over previous
//
#include <hip/hip_runtime.h>

#define BB   1024
#define TT   512
#define NIN  28
#define NOUT 28
#define NS   4
#define MM   7
#define WW   457          // TT - NIN - NOUT + 1
#define SLEN 519          // MM + 1 + TT - 1
#define EMB  9            // 1 + 1 + MM

#define OUT1_SZ (WW * BB * 144)
#define OUT2_SZ (WW * BB * 28)
#define OUT3_SZ (BB * TT)
#define OUT4_SZ (BB * SLEN)

#define CH   32
#define NCH  (TT / CH)    // 16

typedef float f4 __attribute__((ext_vector_type(4)));

__device__ __forceinline__ f4 ld4u(const float* p) {   // 4B-aligned 16B load
    f4 v;
    __builtin_memcpy(&v, p, sizeof(f4));
    return v;
}

// ---------------------------------------------------------------------------
// Kernel 1: ES scan (unchanged, ~10 us). Plain stores keep levels/seas L2-hot
// for k_out1's staging reads.
// ---------------------------------------------------------------------------
__global__ __launch_bounds__(64) void es_scan(const float* __restrict__ Y,
        const int* __restrict__ idxs, const float* __restrict__ EW,
        float* __restrict__ levels, float* __restrict__ seas) {
    __shared__ float yl[64][CH + 1];
    __shared__ float se[64][CH + 1];
    const int tid = threadIdx.x;
    const int b0  = blockIdx.x << 6;
    const int b   = b0 + tid;

    const float* e = EW + idxs[b] * EMB;
    const float lev_sms  = 1.0f / (1.0f + __expf(-e[0]));
    const float seas_sms = 1.0f / (1.0f + __expf(-e[1]));
    const float a_l = 1.0f - lev_sms;
    const float a_s = 1.0f - seas_sms;

    float buf[MM];
    const float is0 = __expf(e[2]);
    {
        float* srow = seas + b * SLEN;
        srow[0] = is0;
#pragma unroll
        for (int k = 1; k < MM; ++k) {
            float v = __expf(e[2 + k]);
            srow[k] = v;
            buf[k - 1] = v;
        }
        buf[MM - 1] = is0;
    }

    f4 pf[8];
#pragma unroll
    for (int k = 0; k < 8; ++k) {
        int flat = (k << 6) + tid;
        int r = flat >> 3, q = flat & 7;
        pf[k] = *reinterpret_cast<const f4*>(Y + (b0 + r) * TT + (q << 2));
    }

    float lev = 0.0f;

#define ES_STEP(TTI)                                                        \
    {                                                                       \
        float y  = yreg[TTI];                                               \
        float st = buf[0];                                                  \
        lev = lev_sms * __fdividef(y, st) + a_l * lev;                      \
        float ns = seas_sms * __fdividef(y, lev) + a_s * st;                \
        buf[0] = buf[1]; buf[1] = buf[2]; buf[2] = buf[3];                  \
        buf[3] = buf[4]; buf[4] = buf[5]; buf[5] = buf[6];                  \
        buf[6] = ns;                                                        \
        yl[tid][TTI] = lev;                                                 \
        se[tid][TTI] = ns;                                                  \
    }

    for (int c = 0; c < NCH; ++c) {
        __syncthreads();
#pragma unroll
        for (int k = 0; k < 8; ++k) {
            int flat = (k << 6) + tid;
            int r = flat >> 3, q = flat & 7;
            float* dst = &yl[r][q << 2];
            dst[0] = pf[k].x; dst[1] = pf[k].y; dst[2] = pf[k].z; dst[3] = pf[k].w;
        }
        __syncthreads();
        if (c < NCH - 1) {
#pragma unroll
            for (int k = 0; k < 8; ++k) {
                int flat = (k << 6) + tid;
                int r = flat >> 3, q = flat & 7;
                pf[k] = *reinterpret_cast<const f4*>(
                    Y + (b0 + r) * TT + (c + 1) * CH + (q << 2));
            }
        }

        float yreg[CH];
#pragma unroll
        for (int tt = 0; tt < CH; ++tt) yreg[tt] = yl[tid][tt];

        if (c == 0) {
            lev = __fdividef(yreg[0], is0);
            yl[tid][0] = lev;
            se[tid][0] = is0;
#pragma unroll
            for (int tt = 1; tt < CH; ++tt) ES_STEP(tt)
        } else {
#pragma unroll
            for (int tt = 0; tt < CH; ++tt) ES_STEP(tt)
        }
        __syncthreads();

#pragma unroll
        for (int k = 0; k < CH; ++k) {
            int flat = (k << 6) + tid;
            int r    = flat >> 5;
            int col  = flat & 31;
            levels[(b0 + r) * TT   + c * CH + col]      = yl[r][col];
            seas  [(b0 + r) * SLEN + MM + c * CH + col] = se[r][col];
        }
    }
#undef ES_STEP
}

// ---------------------------------------------------------------------------
// Kernel 2: out1. Identical structure to R9; ONLY change: nt stores
// (suppress L2 write-allocate — R8 counter-proven: FETCH 6.2MB vs 1.5GB).
// ---------------------------------------------------------------------------
#define PD 129            // padded inner slot count (16B-aligned, bank-staggered)

__global__ __launch_bounds__(256) void k_out1(const float* __restrict__ S,
        const float* __restrict__ Y, const float* __restrict__ X,
        const float* __restrict__ levels, const float* __restrict__ seas,
        f4* __restrict__ out1) {
    __shared__ f4    Xr[4 * 2 * 2 * PD];   // [s][bl][ch][slot]
    __shared__ f4    LYSr[4 * 2 * PD];     // [s][bl][slot]
    __shared__ float LL[2][512];
    __shared__ float LYSp[2][520];

    const int tid = threadIdx.x;
    const int b0  = blockIdx.x << 1;

    // phase 0: per-element logs (coalesced global reads, all L2-hot)
    for (int u = tid; u < 1024; u += 256) {
        int bl = u >> 9, t = u & 511;
        int b  = b0 + bl;
        LL[bl][t]   = __logf(levels[b * TT + t]);
        LYSp[bl][t] = __logf(Y[b * TT + t]) - __logf(seas[b * SLEN + t]);
    }
    __syncthreads();

    // phase 1: build shifted replicas
    for (int u = tid; u < 1024; u += 256) {        // LYSr (s, bl, k)
        int s = u >> 8, r = u & 255, bl = r >> 7, k = r & 127;
        int base = 4 * k + s;                      // <= 511; +3 <= 514 < 520
        f4 v;
        v.x = LYSp[bl][base];     v.y = LYSp[bl][base + 1];
        v.z = LYSp[bl][base + 2]; v.w = LYSp[bl][base + 3];
        LYSr[(s * 2 + bl) * PD + k] = v;
    }
    for (int u = tid; u < 2048; u += 256) {        // Xr (s, bl, ch, k)
        int s = u >> 9, r = u & 511, bl = r >> 8, ch = (r >> 7) & 1, k = r & 127;
        int start = 4 * k + s; if (start > 508) start = 508;
        Xr[((s * 2 + bl) * 2 + ch) * PD + k] =
            ld4u(X + (size_t)((b0 + bl) * 2 + ch) * TT + start);
    }
    f4 Sv0 = *reinterpret_cast<const f4*>(S + b0 * NS);
    f4 Sv1 = *reinterpret_cast<const f4*>(S + (b0 + 1) * NS);
    __syncthreads();

    // main: flat (w, bl, col) — dense full-line NT stores
    for (int j = tid; j < WW * 72; j += 256) {
        int g   = j / 72;                           // w
        int r   = j - g * 72;
        int bl  = (r >= 36) ? 1 : 0;
        int col = r - 36 * bl;
        int s   = g & 3;
        int whi = g >> 2;
        f4 v;
        if (col < 7) {                              // log insample
            f4 t = LYSr[(s * 2 + bl) * PD + whi + col];
            float ll = LL[bl][g + 27];
            v.x = t.x - ll; v.y = t.y - ll; v.z = t.z - ll; v.w = t.w - ll;
        } else if (col < 35) {                      // X windows
            int ch = (col >= 21) ? 1 : 0;
            int jj = col - 7 - 14 * ch;             // 0..13
            v = Xr[((s * 2 + bl) * 2 + ch) * PD + whi + jj];
        } else {                                    // statics
            v = bl ? Sv1 : Sv0;
        }
        __builtin_nontemporal_store(v, &out1[((g << 10) + b0 + bl) * 36 + col]);
    }
}

// ---------------------------------------------------------------------------
// Kernel 3: out2 + out5. Identical to R9; ONLY change: nt stores.
// ---------------------------------------------------------------------------
#define NF2 (WW * BB * 7)

__global__ __launch_bounds__(256) void k_out25(const float* __restrict__ Y,
        const float* __restrict__ mask, f4* __restrict__ out2,
        f4* __restrict__ out5) {
    int i = blockIdx.x * blockDim.x + threadIdx.x;
    const int stride = gridDim.x * blockDim.x;
    for (; i < NF2; i += stride) {
        int wb = i / 7;
        int j  = i - wb * 7;
        int b  = wb & (BB - 1);
        int w  = wb >> 10;
        int base = w + NIN + (j << 2);
        f4 vy = ld4u(Y    + b * TT + base);
        f4 vm = ld4u(mask + b * TT + base);
        __builtin_nontemporal_store(vy, &out2[i]);
        __builtin_nontemporal_store(vm, &out5[i]);
    }
}

extern "C" void kernel_launch(void* const* d_in, const int* in_sizes, int n_in,
                              void* d_out, int out_size, void* d_ws, size_t ws_size,
                              hipStream_t stream) {
    const float* S    = (const float*)d_in[0];
    const float* Y    = (const float*)d_in[1];
    const float* X    = (const float*)d_in[2];
    const int*   idxs = (const int*)d_in[3];
    const float* mask = (const float*)d_in[4];
    const float* EW   = (const float*)d_in[5];

    float* out  = (float*)d_out;
    float* out1 = out;
    float* out2 = out1 + OUT1_SZ;
    float* out3 = out2 + OUT2_SZ;        // levels
    float* out4 = out3 + OUT3_SZ;        // seasonalities
    float* out5 = out4 + OUT4_SZ;        // mask_w

    es_scan<<<16, 64, 0, stream>>>(Y, idxs, EW, out3, out4);
    k_out1<<<BB / 2, 256, 0, stream>>>(S, Y, X, out3, out4, (f4*)out1);
    k_out25<<<2048, 256, 0, stream>>>(Y, mask, (f4*)out2, (f4*)out5);
}